// Round 13
// baseline (499.974 us; speedup 1.0000x reference)
//
#include <hip/hip_runtime.h>
#include <cstdint>

// ---------------------------------------------------------------------------
// WindowAttention (Swin): B_WIN=4096 windows, N=49 tokens, DIM=256, HEADS=8,
// head_dim=32, NW=64 masks.
// S12 = S11 geometry (256-thr blocks, wave = 2 heads, LDS 51.2KB, 3 blocks/CU
// target) with the two S11 deviations reverted to S10-proven form:
//   - P full [64][72] stride 4608, strictly wave-private (no cross-wave reads)
//   - softmax unguarded (no divergent branch; pad rows are row-local garbage,
//     discarded at output — S10-verified safe)
// ---------------------------------------------------------------------------

typedef __attribute__((ext_vector_type(8))) short short8;   // bf16x8 frag
typedef __attribute__((ext_vector_type(4))) float floatx4;  // fp32x4 acc frag

__device__ __forceinline__ ushort f2bf(float f) {
    uint32_t u = __float_as_uint(f);
    u += 0x7FFFu + ((u >> 16) & 1u);   // RNE
    return (ushort)(u >> 16);
}

__device__ __forceinline__ uint32_t cvtpk(float lo, float hi) {
    uint32_t r;
    asm("v_cvt_pk_bf16_f32 %0, %1, %2" : "=v"(r) : "v"(lo), "v"(hi));
    return r;
}

__device__ __forceinline__ uint2 shfl2(uint2 v, int lane) {
    uint2 r;
    r.x = (uint32_t)__shfl((int)v.x, lane, 64);
    r.y = (uint32_t)__shfl((int)v.y, lane, 64);
    return r;
}

// ---------------------------------------------------------------- kernel 0b
__global__ __launch_bounds__(256) void k_cvt_w(const float* __restrict__ qw,
                                               const float* __restrict__ pw,
                                               ushort* __restrict__ qwb,
                                               ushort* __restrict__ pwb) {
    int i = blockIdx.x * 256 + threadIdx.x;
    if (i < 196608) qwb[i] = f2bf(qw[i]);
    else            pwb[i - 196608] = f2bf(pw[i - 196608]);
}

// ---------------------------------------------------------------- kernel 0c
// comb[wh][n][m] padded to stride 64: comb[wh*4096 + n*64 + m], m-pad zeroed.
__global__ __launch_bounds__(256) void k_comb(const float* __restrict__ mask,
                                              const int* __restrict__ rel,
                                              const float* __restrict__ bt,
                                              float* __restrict__ comb) {
    const int wh = blockIdx.x;
    const int w = wh >> 3, h = wh & 7;
    const float* mw = mask + (size_t)w * 2401;
    float* out = comb + (size_t)wh * 4096;
    for (int e = threadIdx.x; e < 49 * 64; e += 256) {
        const int n = e >> 6, m = e & 63;
        out[e] = (m < 49) ? mw[n * 49 + m] + bt[rel[n * 49 + m] * 8 + h] : 0.0f;
    }
}

// ---------------------------------------------------------------- kernel 1
// Monolithic per-window kernel. 256 thr (4 waves), wave w = heads 2w, 2w+1.
// LDS (ushort units), total 25600 ush = 51,200 B:
//   xb     [0,16384)      : x bf16 [64][256], 16B-chunk j^(n&7) swizzle
//   vtw[w] 16384 + w*2304 : [32][72] v transposed (per wave, reused h0->h1)
//   P[w]   w*4608         : [64][72] FULL, wave-private. P[3] tail overlaps
//          vtw[0] only — dead (all vf loaded pre-barrier).
//   ao     [0,16896)      : [64][264] — aliases xb/P after barrier 2
// Barriers: stage-x | GEMMs done | PV done | ao stored.
__global__ __launch_bounds__(256, 3) void k_mono(
        const ushort* __restrict__ qwb, const float* __restrict__ x,
        const float* __restrict__ qb, const float* __restrict__ comb,
        const ushort* __restrict__ pwb, const float* __restrict__ pb,
        float* __restrict__ out) {
    __shared__ ushort smem[25600];   // 51,200 B
    ushort* xb = smem;

    const int t = threadIdx.x;
    const int w = t >> 6, l = t & 63;
    const int g = l >> 4, li = l & 15;
    const int blk = blockIdx.x;
    const int wdw = blk & 63;

    ushort* vtw = smem + 16384 + w * 2304;   // [32][72]
    ushort* P   = smem + w * 4608;           // [64][72] full, wave-private
    ushort* ao  = smem;                      // [64][264]

    const floatx4 zf = {0.f, 0.f, 0.f, 0.f};
    const float scale = 0.17677669529663687f;  // 32^-0.5

    // ---- phase 0: stage x -> xb (bf16, 16B-chunk j^(n&7) swizzle) ----
#pragma unroll
    for (int rep = 0; rep < 2; ++rep) {
        const int n = (t >> 3) + rep * 32;
        const int seg = t & 7;
        if (n < 49) {
            const float* src = x + ((size_t)blk * 49 + n) * 256 + seg * 32;
#pragma unroll
            for (int c4 = 0; c4 < 4; ++c4) {
                const float4 a  = *(const float4*)(src + c4 * 8);
                const float4 b2 = *(const float4*)(src + c4 * 8 + 4);
                uint4 u;
                u.x = cvtpk(a.x, a.y);  u.y = cvtpk(a.z, a.w);
                u.z = cvtpk(b2.x, b2.y); u.w = cvtpk(b2.z, b2.w);
                const int j = seg * 4 + c4;
                *(uint4*)(xb + n * 256 + ((j ^ (n & 7)) * 8)) = u;
            }
        } else {
            const uint4 z = {0u, 0u, 0u, 0u};
#pragma unroll
            for (int c4 = 0; c4 < 4; ++c4) {
                const int j = seg * 4 + c4;
                *(uint4*)(xb + n * 256 + ((j ^ (n & 7)) * 8)) = z;
            }
        }
    }
    __syncthreads();

    // one GEMM pass: 2 c-tiles (W rows BASE, BASE+16), acc[2][4].
    // acc[ct][nt] lane map: c = BASE + ct*16 + g*4 + r, n = nt*16 + li.
    floatx4 acc[2][4];
#define GEMM_PASS(BASE)                                                       \
    {                                                                         \
        _Pragma("unroll")                                                     \
        for (int i = 0; i < 2; ++i)                                           \
            _Pragma("unroll")                                                 \
            for (int j = 0; j < 4; ++j) acc[i][j] = zf;                       \
        _Pragma("unroll")                                                     \
        for (int kt = 0; kt < 8; ++kt) {                                      \
            const short8 af0 = *(const short8*)(qwb +                         \
                (size_t)((BASE) + li) * 256 + kt * 32 + g * 8);               \
            const short8 af1 = *(const short8*)(qwb +                         \
                (size_t)((BASE) + 16 + li) * 256 + kt * 32 + g * 8);          \
            _Pragma("unroll")                                                 \
            for (int nt = 0; nt < 4; ++nt) {                                  \
                const short8 bx = *(const short8*)(xb +                       \
                    (nt * 16 + li) * 256 + (((kt * 4 + g) ^ (li & 7)) * 8));  \
                acc[0][nt] = __builtin_amdgcn_mfma_f32_16x16x32_bf16(         \
                    af0, bx, acc[0][nt], 0, 0, 0);                            \
                acc[1][nt] = __builtin_amdgcn_mfma_f32_16x16x32_bf16(         \
                    af1, bx, acc[1][nt], 0, 0, 0);                            \
            }                                                                 \
        }                                                                     \
    }

    // acc (+bias) -> B-operand frag via in-register transpose (S10-verified).
#define XPOSE_QK(CBASE, OUTF)                                                 \
    {                                                                         \
        uint2 u2[2][4];                                                       \
        _Pragma("unroll")                                                     \
        for (int ct = 0; ct < 2; ++ct) {                                      \
            const float4 b4 = *(const float4*)(qb + (CBASE) + ct * 16 + g * 4);\
            _Pragma("unroll")                                                 \
            for (int nt = 0; nt < 4; ++nt) {                                  \
                u2[ct][nt].x = cvtpk(acc[ct][nt][0] + b4.x,                   \
                                     acc[ct][nt][1] + b4.y);                  \
                u2[ct][nt].y = cvtpk(acc[ct][nt][2] + b4.z,                   \
                                     acc[ct][nt][3] + b4.w);                  \
            }                                                                 \
        }                                                                     \
        const int src0 = li + (g & 1) * 32, src1 = src0 + 16;                 \
        _Pragma("unroll")                                                     \
        for (int mt = 0; mt < 4; ++mt) {                                      \
            const uint2 a0 = shfl2(u2[0][mt], src0);                          \
            const uint2 a1 = shfl2(u2[0][mt], src1);                          \
            const uint2 b0 = shfl2(u2[1][mt], src0);                          \
            const uint2 b1 = shfl2(u2[1][mt], src1);                          \
            union { short8 s; uint32_t q[4]; } cv;                            \
            cv.q[0] = (g < 2) ? a0.x : b0.x;                                  \
            cv.q[1] = (g < 2) ? a0.y : b0.y;                                  \
            cv.q[2] = (g < 2) ? a1.x : b1.x;                                  \
            cv.q[3] = (g < 2) ? a1.y : b1.y;                                  \
            OUTF[mt] = cv.s;                                                  \
        }                                                                     \
    }

    // ---- GEMM passes for both heads (xb live throughout) ----
    short8 qf[2][4], kf[2][4], vf[2][2][2];
#pragma unroll
    for (int hh = 0; hh < 2; ++hh) {
        const int hd = w * 2 + hh;
        GEMM_PASS(hd * 32)
        XPOSE_QK(hd * 32, qf[hh])
        GEMM_PASS(256 + hd * 32)
        XPOSE_QK(256 + hd * 32, kf[hh])
        GEMM_PASS(512 + hd * 32)
        // V epilogue -> vtw (transposed [dd][n]), then frags (region reused)
#pragma unroll
        for (int ct = 0; ct < 2; ++ct) {
            const int dd0 = ct * 16 + g * 4;
            const float4 b4 = *(const float4*)(qb + 512 + hd * 32 + dd0);
#pragma unroll
            for (int nt = 0; nt < 4; ++nt) {
                const int n = nt * 16 + li;
                vtw[(dd0 + 0) * 72 + n] = f2bf(acc[ct][nt][0] + b4.x);
                vtw[(dd0 + 1) * 72 + n] = f2bf(acc[ct][nt][1] + b4.y);
                vtw[(dd0 + 2) * 72 + n] = f2bf(acc[ct][nt][2] + b4.z);
                vtw[(dd0 + 3) * 72 + n] = f2bf(acc[ct][nt][3] + b4.w);
            }
        }
#pragma unroll
        for (int ks = 0; ks < 2; ++ks)
#pragma unroll
            for (int nt = 0; nt < 2; ++nt)
                vf[hh][ks][nt] = *(const short8*)(vtw + (nt * 16 + li) * 72 +
                                                  ks * 32 + g * 8);
    }
    __syncthreads();   // xb + all vtw dead: P (aliasing them) may be written

    // ---- attention per head (S10 math verbatim, unguarded softmax) ----
    floatx4 oac[2][4][2];
#pragma unroll
    for (int hh = 0; hh < 2; ++hh) {
        const int hd = w * 2 + hh;
        const float* cw = comb + (size_t)(wdw * 8 + hd) * 4096;
#pragma unroll
        for (int bq = 0; bq < 4; ++bq) {
            floatx4 sac[4];
#pragma unroll
            for (int ak = 0; ak < 4; ++ak)
                sac[ak] = __builtin_amdgcn_mfma_f32_16x16x32_bf16(
                    kf[hh][ak], qf[hh][bq], zf, 0, 0, 0);

            const int n = bq * 16 + li;
            const float* cr = cw + n * 64 + g * 4;
            const float4 c0 = *(const float4*)(cr);
            const float4 c1 = *(const float4*)(cr + 16);
            const float4 c2 = *(const float4*)(cr + 32);
            const float c3x = cr[48];
            float v[12];
            v[0]  = sac[0][0] * scale + c0.x;
            v[1]  = sac[0][1] * scale + c0.y;
            v[2]  = sac[0][2] * scale + c0.z;
            v[3]  = sac[0][3] * scale + c0.w;
            v[4]  = sac[1][0] * scale + c1.x;
            v[5]  = sac[1][1] * scale + c1.y;
            v[6]  = sac[1][2] * scale + c1.z;
            v[7]  = sac[1][3] * scale + c1.w;
            v[8]  = sac[2][0] * scale + c2.x;
            v[9]  = sac[2][1] * scale + c2.y;
            v[10] = sac[2][2] * scale + c2.z;
            v[11] = sac[2][3] * scale + c2.w;
            const float v48 = (g == 0) ? sac[3][0] * scale + c3x : -3.0e38f;
            float mx = fmaxf(fmaxf(fmaxf(v[0], v[1]), fmaxf(v[2], v[3])),
                             fmaxf(fmaxf(v[4], v[5]), fmaxf(v[6], v[7])));
            mx = fmaxf(mx, fmaxf(fmaxf(v[8], v[9]), fmaxf(v[10], v[11])));
            mx = fmaxf(mx, v48);
            mx = fmaxf(mx, __shfl_xor(mx, 16, 64));
            mx = fmaxf(mx, __shfl_xor(mx, 32, 64));
            float e[12], s = 0.f;
#pragma unroll
            for (int i = 0; i < 12; ++i) { e[i] = __expf(v[i] - mx); s += e[i]; }
            const float e48 = __expf(v48 - mx);   // exactly 0 for g>0
            s += e48;
            s += __shfl_xor(s, 16, 64);
            s += __shfl_xor(s, 32, 64);
            const float inv = 1.0f / s;
            uint2 pk;
#pragma unroll
            for (int a = 0; a < 3; ++a) {
                pk.x = cvtpk(e[a * 4 + 0] * inv, e[a * 4 + 1] * inv);
                pk.y = cvtpk(e[a * 4 + 2] * inv, e[a * 4 + 3] * inv);
                *(uint2*)(P + n * 72 + a * 16 + g * 4) = pk;
            }
            pk.x = cvtpk(e48 * inv, 0.f);
            pk.y = 0u;
            *(uint2*)(P + n * 72 + 48 + g * 4) = pk;   // cols 49..63 exact 0
        }

        // O = P V (wave-private; hh=0's PV completes before hh=1 rewrites P)
#pragma unroll
        for (int mt = 0; mt < 4; ++mt)
#pragma unroll
            for (int nt = 0; nt < 2; ++nt) oac[hh][mt][nt] = zf;
#pragma unroll
        for (int ks = 0; ks < 2; ++ks)
#pragma unroll
            for (int mt = 0; mt < 4; ++mt) {
                const short8 pf = *(const short8*)(P + (mt * 16 + li) * 72 +
                                                   ks * 32 + g * 8);
                oac[hh][mt][0] = __builtin_amdgcn_mfma_f32_16x16x32_bf16(
                    pf, vf[hh][ks][0], oac[hh][mt][0], 0, 0, 0);
                oac[hh][mt][1] = __builtin_amdgcn_mfma_f32_16x16x32_bf16(
                    pf, vf[hh][ks][1], oac[hh][mt][1], 0, 0, 0);
            }
    }

    __syncthreads();   // all waves done with P: ao may overwrite

    // ---- store O into ao[n][hd*32+dd]; zero pad rows (wave: 64 cols) ----
#pragma unroll
    for (int hh = 0; hh < 2; ++hh) {
        const int hd = w * 2 + hh;
#pragma unroll
        for (int mt = 0; mt < 4; ++mt)
#pragma unroll
            for (int rr = 0; rr < 4; ++rr) {
                const int n = mt * 16 + g * 4 + rr;
                if (n < 49) {
#pragma unroll
                    for (int nt = 0; nt < 2; ++nt)
                        ao[n * 264 + hd * 32 + nt * 16 + li] =
                            f2bf(oac[hh][mt][nt][rr]);
                }
            }
    }
    for (int idx = l; idx < 480; idx += 64) {
        const int n = 49 + (idx >> 5);
        const int du = idx & 31;
        *(uint32_t*)(ao + n * 264 + w * 64 + du * 2) = 0u;
    }
    __syncthreads();

    // ---- proj: wave w covers cols w*64..w*64+63; pacc[4][4] ----
    floatx4 pacc[4][4];
#pragma unroll
    for (int mt = 0; mt < 4; ++mt)
#pragma unroll
        for (int nt = 0; nt < 4; ++nt) pacc[mt][nt] = zf;
#pragma unroll
    for (int kt = 0; kt < 8; ++kt) {
        short8 afr[4], wfr[4];
#pragma unroll
        for (int mt = 0; mt < 4; ++mt)
            afr[mt] = *(const short8*)(ao + (mt * 16 + li) * 264 + kt * 32 + g * 8);
#pragma unroll
        for (int nt = 0; nt < 4; ++nt)
            wfr[nt] = *(const short8*)(pwb +
                (size_t)(w * 64 + nt * 16 + li) * 256 + kt * 32 + g * 8);
#pragma unroll
        for (int mt = 0; mt < 4; ++mt)
#pragma unroll
            for (int nt = 0; nt < 4; ++nt)
                pacc[mt][nt] = __builtin_amdgcn_mfma_f32_16x16x32_bf16(
                    afr[mt], wfr[nt], pacc[mt][nt], 0, 0, 0);
    }

    float* og = out + (size_t)blk * 49 * 256;
#pragma unroll
    for (int nt = 0; nt < 4; ++nt) {
        const int c = w * 64 + nt * 16 + li;
        const float bias = pb[c];
#pragma unroll
        for (int mt = 0; mt < 4; ++mt)
#pragma unroll
            for (int r = 0; r < 4; ++r) {
                const int n = mt * 16 + g * 4 + r;
                if (n < 49) og[(size_t)n * 256 + c] = pacc[mt][nt][r] + bias;
            }
    }
#undef GEMM_PASS
#undef XPOSE_QK
}

// ---------------------------------------------------------------------------
extern "C" void kernel_launch(void* const* d_in, const int* in_sizes, int n_in,
                              void* d_out, int out_size, void* d_ws, size_t ws_size,
                              hipStream_t stream) {
    const float* x      = (const float*)d_in[0];
    const float* mask   = (const float*)d_in[1];
    const int*   rel    = (const int*)d_in[2];
    const float* qkv_w  = (const float*)d_in[3];
    const float* qkv_b  = (const float*)d_in[4];
    const float* proj_w = (const float*)d_in[5];
    const float* proj_b = (const float*)d_in[6];
    const float* bt     = (const float*)d_in[7];
    float* out = (float*)d_out;

    // ws layout (bytes); total = 8,912,896 (~8.5 MiB)
    char* ws = (char*)d_ws;
    ushort* qwb  = (ushort*)(ws);                  // 768*256 bf16   (393216 B)
    ushort* pwb  = (ushort*)(ws + 393216);         // 256*256 bf16   (131072 B)
    float*  comb = (float*) (ws + 524288);         // 512*64*64 f32  (8388608 B)
    (void)ws_size; (void)in_sizes; (void)n_in; (void)out_size;

    k_cvt_w<<<dim3(1024), dim3(256), 0, stream>>>(qkv_w, proj_w, qwb, pwb);
    k_comb <<<dim3(512),  dim3(256), 0, stream>>>(mask, rel, bt, comb);
    k_mono <<<dim3(4096), dim3(256), 0, stream>>>(qwb, x, qkv_b, comb, pwb,
                                                  proj_b, out);
}

// Round 15
// 394.780 us; speedup vs baseline: 1.2665x; 1.2665x over previous
//
#include <hip/hip_runtime.h>
#include <cstdint>

// ---------------------------------------------------------------------------
// WindowAttention (Swin): B_WIN=4096 windows, N=49 tokens, DIM=256, HEADS=8,
// head_dim=32, NW=64 masks.
// S15 = S12 (round-13, PASSING) with exactly ONE change:
// __launch_bounds__(256,3) -> (256,2). The 170-reg cap of (256,3) forced
// ~500MB of scratch spills (WRITE 713MB); (256,2) gives a 256-reg budget ->
// no spills, 2 independent blocks/CU (8 waves/CU with cross-block overlap).
// All math byte-identical to S12.
// ---------------------------------------------------------------------------

typedef __attribute__((ext_vector_type(8))) short short8;   // bf16x8 frag
typedef __attribute__((ext_vector_type(4))) float floatx4;  // fp32x4 acc frag

__device__ __forceinline__ ushort f2bf(float f) {
    uint32_t u = __float_as_uint(f);
    u += 0x7FFFu + ((u >> 16) & 1u);   // RNE
    return (ushort)(u >> 16);
}

__device__ __forceinline__ uint32_t cvtpk(float lo, float hi) {
    uint32_t r;
    asm("v_cvt_pk_bf16_f32 %0, %1, %2" : "=v"(r) : "v"(lo), "v"(hi));
    return r;
}

__device__ __forceinline__ uint2 shfl2(uint2 v, int lane) {
    uint2 r;
    r.x = (uint32_t)__shfl((int)v.x, lane, 64);
    r.y = (uint32_t)__shfl((int)v.y, lane, 64);
    return r;
}

// ---------------------------------------------------------------- kernel 0b
__global__ __launch_bounds__(256) void k_cvt_w(const float* __restrict__ qw,
                                               const float* __restrict__ pw,
                                               ushort* __restrict__ qwb,
                                               ushort* __restrict__ pwb) {
    int i = blockIdx.x * 256 + threadIdx.x;
    if (i < 196608) qwb[i] = f2bf(qw[i]);
    else            pwb[i - 196608] = f2bf(pw[i - 196608]);
}

// ---------------------------------------------------------------- kernel 0c
// comb[wh][n][m] padded to stride 64: comb[wh*4096 + n*64 + m], m-pad zeroed.
__global__ __launch_bounds__(256) void k_comb(const float* __restrict__ mask,
                                              const int* __restrict__ rel,
                                              const float* __restrict__ bt,
                                              float* __restrict__ comb) {
    const int wh = blockIdx.x;
    const int w = wh >> 3, h = wh & 7;
    const float* mw = mask + (size_t)w * 2401;
    float* out = comb + (size_t)wh * 4096;
    for (int e = threadIdx.x; e < 49 * 64; e += 256) {
        const int n = e >> 6, m = e & 63;
        out[e] = (m < 49) ? mw[n * 49 + m] + bt[rel[n * 49 + m] * 8 + h] : 0.0f;
    }
}

// ---------------------------------------------------------------- kernel 1
// Monolithic per-window kernel. 256 thr (4 waves), wave w = heads 2w, 2w+1.
// LDS (ushort units), total 25600 ush = 51,200 B:
//   xb     [0,16384)      : x bf16 [64][256], 16B-chunk j^(n&7) swizzle
//   vtw[w] 16384 + w*2304 : [32][72] v transposed (per wave, reused h0->h1)
//   P[w]   w*4608         : [64][72] FULL, wave-private. P[3] tail overlaps
//          vtw[0] only — dead (all vf loaded pre-barrier).
//   ao     [0,16896)      : [64][264] — aliases xb/P after barrier 2
// Barriers: stage-x | GEMMs done | PV done | ao stored.
__global__ __launch_bounds__(256, 2) void k_mono(
        const ushort* __restrict__ qwb, const float* __restrict__ x,
        const float* __restrict__ qb, const float* __restrict__ comb,
        const ushort* __restrict__ pwb, const float* __restrict__ pb,
        float* __restrict__ out) {
    __shared__ ushort smem[25600];   // 51,200 B
    ushort* xb = smem;

    const int t = threadIdx.x;
    const int w = t >> 6, l = t & 63;
    const int g = l >> 4, li = l & 15;
    const int blk = blockIdx.x;
    const int wdw = blk & 63;

    ushort* vtw = smem + 16384 + w * 2304;   // [32][72]
    ushort* P   = smem + w * 4608;           // [64][72] full, wave-private
    ushort* ao  = smem;                      // [64][264]

    const floatx4 zf = {0.f, 0.f, 0.f, 0.f};
    const float scale = 0.17677669529663687f;  // 32^-0.5

    // ---- phase 0: stage x -> xb (bf16, 16B-chunk j^(n&7) swizzle) ----
#pragma unroll
    for (int rep = 0; rep < 2; ++rep) {
        const int n = (t >> 3) + rep * 32;
        const int seg = t & 7;
        if (n < 49) {
            const float* src = x + ((size_t)blk * 49 + n) * 256 + seg * 32;
#pragma unroll
            for (int c4 = 0; c4 < 4; ++c4) {
                const float4 a  = *(const float4*)(src + c4 * 8);
                const float4 b2 = *(const float4*)(src + c4 * 8 + 4);
                uint4 u;
                u.x = cvtpk(a.x, a.y);  u.y = cvtpk(a.z, a.w);
                u.z = cvtpk(b2.x, b2.y); u.w = cvtpk(b2.z, b2.w);
                const int j = seg * 4 + c4;
                *(uint4*)(xb + n * 256 + ((j ^ (n & 7)) * 8)) = u;
            }
        } else {
            const uint4 z = {0u, 0u, 0u, 0u};
#pragma unroll
            for (int c4 = 0; c4 < 4; ++c4) {
                const int j = seg * 4 + c4;
                *(uint4*)(xb + n * 256 + ((j ^ (n & 7)) * 8)) = z;
            }
        }
    }
    __syncthreads();

    // one GEMM pass: 2 c-tiles (W rows BASE, BASE+16), acc[2][4].
    // acc[ct][nt] lane map: c = BASE + ct*16 + g*4 + r, n = nt*16 + li.
    floatx4 acc[2][4];
#define GEMM_PASS(BASE)                                                       \
    {                                                                         \
        _Pragma("unroll")                                                     \
        for (int i = 0; i < 2; ++i)                                           \
            _Pragma("unroll")                                                 \
            for (int jj = 0; jj < 4; ++jj) acc[i][jj] = zf;                   \
        _Pragma("unroll")                                                     \
        for (int kt = 0; kt < 8; ++kt) {                                      \
            const short8 af0 = *(const short8*)(qwb +                         \
                (size_t)((BASE) + li) * 256 + kt * 32 + g * 8);               \
            const short8 af1 = *(const short8*)(qwb +                         \
                (size_t)((BASE) + 16 + li) * 256 + kt * 32 + g * 8);          \
            _Pragma("unroll")                                                 \
            for (int nt = 0; nt < 4; ++nt) {                                  \
                const short8 bx = *(const short8*)(xb +                       \
                    (nt * 16 + li) * 256 + (((kt * 4 + g) ^ (li & 7)) * 8));  \
                acc[0][nt] = __builtin_amdgcn_mfma_f32_16x16x32_bf16(         \
                    af0, bx, acc[0][nt], 0, 0, 0);                            \
                acc[1][nt] = __builtin_amdgcn_mfma_f32_16x16x32_bf16(         \
                    af1, bx, acc[1][nt], 0, 0, 0);                            \
            }                                                                 \
        }                                                                     \
    }

    // acc (+bias) -> B-operand frag via in-register transpose (S10/S12-proven)
#define XPOSE_QK(CBASE, OUTF)                                                 \
    {                                                                         \
        uint2 u2[2][4];                                                       \
        _Pragma("unroll")                                                     \
        for (int ct = 0; ct < 2; ++ct) {                                      \
            const float4 b4 = *(const float4*)(qb + (CBASE) + ct * 16 + g * 4);\
            _Pragma("unroll")                                                 \
            for (int nt = 0; nt < 4; ++nt) {                                  \
                u2[ct][nt].x = cvtpk(acc[ct][nt][0] + b4.x,                   \
                                     acc[ct][nt][1] + b4.y);                  \
                u2[ct][nt].y = cvtpk(acc[ct][nt][2] + b4.z,                   \
                                     acc[ct][nt][3] + b4.w);                  \
            }                                                                 \
        }                                                                     \
        const int src0 = li + (g & 1) * 32, src1 = src0 + 16;                 \
        _Pragma("unroll")                                                     \
        for (int mt = 0; mt < 4; ++mt) {                                      \
            const uint2 a0 = shfl2(u2[0][mt], src0);                          \
            const uint2 a1 = shfl2(u2[0][mt], src1);                          \
            const uint2 b0 = shfl2(u2[1][mt], src0);                          \
            const uint2 b1 = shfl2(u2[1][mt], src1);                          \
            union { short8 s; uint32_t q[4]; } cv;                            \
            cv.q[0] = (g < 2) ? a0.x : b0.x;                                  \
            cv.q[1] = (g < 2) ? a0.y : b0.y;                                  \
            cv.q[2] = (g < 2) ? a1.x : b1.x;                                  \
            cv.q[3] = (g < 2) ? a1.y : b1.y;                                  \
            OUTF[mt] = cv.s;                                                  \
        }                                                                     \
    }

    // ---- GEMM passes for both heads (xb live throughout) ----
    short8 qf[2][4], kf[2][4], vf[2][2][2];
#pragma unroll
    for (int hh = 0; hh < 2; ++hh) {
        const int hd = w * 2 + hh;
        GEMM_PASS(hd * 32)
        XPOSE_QK(hd * 32, qf[hh])
        GEMM_PASS(256 + hd * 32)
        XPOSE_QK(256 + hd * 32, kf[hh])
        GEMM_PASS(512 + hd * 32)
        // V epilogue -> vtw (transposed [dd][n]), then frags (region reused)
#pragma unroll
        for (int ct = 0; ct < 2; ++ct) {
            const int dd0 = ct * 16 + g * 4;
            const float4 b4 = *(const float4*)(qb + 512 + hd * 32 + dd0);
#pragma unroll
            for (int nt = 0; nt < 4; ++nt) {
                const int n = nt * 16 + li;
                vtw[(dd0 + 0) * 72 + n] = f2bf(acc[ct][nt][0] + b4.x);
                vtw[(dd0 + 1) * 72 + n] = f2bf(acc[ct][nt][1] + b4.y);
                vtw[(dd0 + 2) * 72 + n] = f2bf(acc[ct][nt][2] + b4.z);
                vtw[(dd0 + 3) * 72 + n] = f2bf(acc[ct][nt][3] + b4.w);
            }
        }
#pragma unroll
        for (int ks = 0; ks < 2; ++ks)
#pragma unroll
            for (int nt = 0; nt < 2; ++nt)
                vf[hh][ks][nt] = *(const short8*)(vtw + (nt * 16 + li) * 72 +
                                                  ks * 32 + g * 8);
    }
    __syncthreads();   // xb + all vtw dead: P (aliasing them) may be written

    // ---- attention per head (S10 math verbatim, unguarded softmax) ----
    floatx4 oac[2][4][2];
#pragma unroll
    for (int hh = 0; hh < 2; ++hh) {
        const int hd = w * 2 + hh;
        const float* cw = comb + (size_t)(wdw * 8 + hd) * 4096;
#pragma unroll
        for (int bq = 0; bq < 4; ++bq) {
            floatx4 sac[4];
#pragma unroll
            for (int ak = 0; ak < 4; ++ak)
                sac[ak] = __builtin_amdgcn_mfma_f32_16x16x32_bf16(
                    kf[hh][ak], qf[hh][bq], zf, 0, 0, 0);

            const int n = bq * 16 + li;
            const float* cr = cw + n * 64 + g * 4;
            const float4 c0 = *(const float4*)(cr);
            const float4 c1 = *(const float4*)(cr + 16);
            const float4 c2 = *(const float4*)(cr + 32);
            const float c3x = cr[48];
            float v[12];
            v[0]  = sac[0][0] * scale + c0.x;
            v[1]  = sac[0][1] * scale + c0.y;
            v[2]  = sac[0][2] * scale + c0.z;
            v[3]  = sac[0][3] * scale + c0.w;
            v[4]  = sac[1][0] * scale + c1.x;
            v[5]  = sac[1][1] * scale + c1.y;
            v[6]  = sac[1][2] * scale + c1.z;
            v[7]  = sac[1][3] * scale + c1.w;
            v[8]  = sac[2][0] * scale + c2.x;
            v[9]  = sac[2][1] * scale + c2.y;
            v[10] = sac[2][2] * scale + c2.z;
            v[11] = sac[2][3] * scale + c2.w;
            const float v48 = (g == 0) ? sac[3][0] * scale + c3x : -3.0e38f;
            float mx = fmaxf(fmaxf(fmaxf(v[0], v[1]), fmaxf(v[2], v[3])),
                             fmaxf(fmaxf(v[4], v[5]), fmaxf(v[6], v[7])));
            mx = fmaxf(mx, fmaxf(fmaxf(v[8], v[9]), fmaxf(v[10], v[11])));
            mx = fmaxf(mx, v48);
            mx = fmaxf(mx, __shfl_xor(mx, 16, 64));
            mx = fmaxf(mx, __shfl_xor(mx, 32, 64));
            float e[12], s = 0.f;
#pragma unroll
            for (int i = 0; i < 12; ++i) { e[i] = __expf(v[i] - mx); s += e[i]; }
            const float e48 = __expf(v48 - mx);   // exactly 0 for g>0
            s += e48;
            s += __shfl_xor(s, 16, 64);
            s += __shfl_xor(s, 32, 64);
            const float inv = 1.0f / s;
            uint2 pk;
#pragma unroll
            for (int a = 0; a < 3; ++a) {
                pk.x = cvtpk(e[a * 4 + 0] * inv, e[a * 4 + 1] * inv);
                pk.y = cvtpk(e[a * 4 + 2] * inv, e[a * 4 + 3] * inv);
                *(uint2*)(P + n * 72 + a * 16 + g * 4) = pk;
            }
            pk.x = cvtpk(e48 * inv, 0.f);
            pk.y = 0u;
            *(uint2*)(P + n * 72 + 48 + g * 4) = pk;   // cols 49..63 exact 0
        }

        // O = P V (wave-private; hh=0's PV completes before hh=1 rewrites P)
#pragma unroll
        for (int mt = 0; mt < 4; ++mt)
#pragma unroll
            for (int nt = 0; nt < 2; ++nt) oac[hh][mt][nt] = zf;
#pragma unroll
        for (int ks = 0; ks < 2; ++ks)
#pragma unroll
            for (int mt = 0; mt < 4; ++mt) {
                const short8 pf = *(const short8*)(P + (mt * 16 + li) * 72 +
                                                   ks * 32 + g * 8);
                oac[hh][mt][0] = __builtin_amdgcn_mfma_f32_16x16x32_bf16(
                    pf, vf[hh][ks][0], oac[hh][mt][0], 0, 0, 0);
                oac[hh][mt][1] = __builtin_amdgcn_mfma_f32_16x16x32_bf16(
                    pf, vf[hh][ks][1], oac[hh][mt][1], 0, 0, 0);
            }
    }

    __syncthreads();   // all waves done with P: ao may overwrite

    // ---- store O into ao[n][hd*32+dd]; zero pad rows (wave: 64 cols) ----
#pragma unroll
    for (int hh = 0; hh < 2; ++hh) {
        const int hd = w * 2 + hh;
#pragma unroll
        for (int mt = 0; mt < 4; ++mt)
#pragma unroll
            for (int rr = 0; rr < 4; ++rr) {
                const int n = mt * 16 + g * 4 + rr;
                if (n < 49) {
#pragma unroll
                    for (int nt = 0; nt < 2; ++nt)
                        ao[n * 264 + hd * 32 + nt * 16 + li] =
                            f2bf(oac[hh][mt][nt][rr]);
                }
            }
    }
    for (int idx = l; idx < 480; idx += 64) {
        const int n = 49 + (idx >> 5);
        const int du = idx & 31;
        *(uint32_t*)(ao + n * 264 + w * 64 + du * 2) = 0u;
    }
    __syncthreads();

    // ---- proj: wave w covers cols w*64..w*64+63; pacc[4][4] ----
    floatx4 pacc[4][4];
#pragma unroll
    for (int mt = 0; mt < 4; ++mt)
#pragma unroll
        for (int nt = 0; nt < 4; ++nt) pacc[mt][nt] = zf;
#pragma unroll
    for (int kt = 0; kt < 8; ++kt) {
        short8 afr[4], wfr[4];
#pragma unroll
        for (int mt = 0; mt < 4; ++mt)
            afr[mt] = *(const short8*)(ao + (mt * 16 + li) * 264 + kt * 32 + g * 8);
#pragma unroll
        for (int nt = 0; nt < 4; ++nt)
            wfr[nt] = *(const short8*)(pwb +
                (size_t)(w * 64 + nt * 16 + li) * 256 + kt * 32 + g * 8);
#pragma unroll
        for (int mt = 0; mt < 4; ++mt)
#pragma unroll
            for (int nt = 0; nt < 4; ++nt)
                pacc[mt][nt] = __builtin_amdgcn_mfma_f32_16x16x32_bf16(
                    afr[mt], wfr[nt], pacc[mt][nt], 0, 0, 0);
    }

    float* og = out + (size_t)blk * 49 * 256;
#pragma unroll
    for (int nt = 0; nt < 4; ++nt) {
        const int c = w * 64 + nt * 16 + li;
        const float bias = pb[c];
#pragma unroll
        for (int mt = 0; mt < 4; ++mt)
#pragma unroll
            for (int r = 0; r < 4; ++r) {
                const int n = mt * 16 + g * 4 + r;
                if (n < 49) og[(size_t)n * 256 + c] = pacc[mt][nt][r] + bias;
            }
    }
#undef GEMM_PASS
#undef XPOSE_QK
}

// ---------------------------------------------------------------------------
extern "C" void kernel_launch(void* const* d_in, const int* in_sizes, int n_in,
                              void* d_out, int out_size, void* d_ws, size_t ws_size,
                              hipStream_t stream) {
    const float* x      = (const float*)d_in[0];
    const float* mask   = (const float*)d_in[1];
    const int*   rel    = (const int*)d_in[2];
    const float* qkv_w  = (const float*)d_in[3];
    const float* qkv_b  = (const float*)d_in[4];
    const float* proj_w = (const float*)d_in[5];
    const float* proj_b = (const float*)d_in[6];
    const float* bt     = (const float*)d_in[7];
    float* out = (float*)d_out;

    // ws layout (bytes); total = 8,912,896 (~8.5 MiB)
    char* ws = (char*)d_ws;
    ushort* qwb  = (ushort*)(ws);                  // 768*256 bf16   (393216 B)
    ushort* pwb  = (ushort*)(ws + 393216);         // 256*256 bf16   (131072 B)
    float*  comb = (float*) (ws + 524288);         // 512*64*64 f32  (8388608 B)
    (void)ws_size; (void)in_sizes; (void)n_in; (void)out_size;

    k_cvt_w<<<dim3(1024), dim3(256), 0, stream>>>(qkv_w, proj_w, qwb, pwb);
    k_comb <<<dim3(512),  dim3(256), 0, stream>>>(mask, rel, bt, comb);
    k_mono <<<dim3(4096), dim3(256), 0, stream>>>(qwb, x, qkv_b, comb, pwb,
                                                  proj_b, out);
}

// Round 17
// 394.027 us; speedup vs baseline: 1.2689x; 1.0019x over previous
//
#include <hip/hip_runtime.h>
#include <cstdint>

// ---------------------------------------------------------------------------
// WindowAttention (Swin): B_WIN=4096 windows, N=49 tokens, DIM=256, HEADS=8,
// head_dim=32, NW=64 masks.
// S17 = S15 (round-15, PASSING, 394.8us) + exactly ONE delta:
//   XCD-bijective block remap (blk = xcd*8 + (jj&7) + (jj>>3)*64): each XCD
//   sees only 8 wdw values -> comb footprint 1MB/XCD (L2-resident; was
//   8.4MB serviced from L3 on the softmax critical path).
// All math and launch bounds byte-identical to S15.
// ---------------------------------------------------------------------------

typedef __attribute__((ext_vector_type(8))) short short8;   // bf16x8 frag
typedef __attribute__((ext_vector_type(4))) float floatx4;  // fp32x4 acc frag

__device__ __forceinline__ ushort f2bf(float f) {
    uint32_t u = __float_as_uint(f);
    u += 0x7FFFu + ((u >> 16) & 1u);   // RNE
    return (ushort)(u >> 16);
}

__device__ __forceinline__ uint32_t cvtpk(float lo, float hi) {
    uint32_t r;
    asm("v_cvt_pk_bf16_f32 %0, %1, %2" : "=v"(r) : "v"(lo), "v"(hi));
    return r;
}

__device__ __forceinline__ uint2 shfl2(uint2 v, int lane) {
    uint2 r;
    r.x = (uint32_t)__shfl((int)v.x, lane, 64);
    r.y = (uint32_t)__shfl((int)v.y, lane, 64);
    return r;
}

// ---------------------------------------------------------------- kernel 0b
__global__ __launch_bounds__(256) void k_cvt_w(const float* __restrict__ qw,
                                               const float* __restrict__ pw,
                                               ushort* __restrict__ qwb,
                                               ushort* __restrict__ pwb) {
    int i = blockIdx.x * 256 + threadIdx.x;
    if (i < 196608) qwb[i] = f2bf(qw[i]);
    else            pwb[i - 196608] = f2bf(pw[i - 196608]);
}

// ---------------------------------------------------------------- kernel 0c
// comb[wh][n][m] padded to stride 64: comb[wh*4096 + n*64 + m], m-pad zeroed.
__global__ __launch_bounds__(256) void k_comb(const float* __restrict__ mask,
                                              const int* __restrict__ rel,
                                              const float* __restrict__ bt,
                                              float* __restrict__ comb) {
    const int wh = blockIdx.x;
    const int w = wh >> 3, h = wh & 7;
    const float* mw = mask + (size_t)w * 2401;
    float* out = comb + (size_t)wh * 4096;
    for (int e = threadIdx.x; e < 49 * 64; e += 256) {
        const int n = e >> 6, m = e & 63;
        out[e] = (m < 49) ? mw[n * 49 + m] + bt[rel[n * 49 + m] * 8 + h] : 0.0f;
    }
}

// ---------------------------------------------------------------- kernel 1
// Monolithic per-window kernel. 256 thr (4 waves), wave w = heads 2w, 2w+1.
// XCD-bijective remap: blk = xcd*8 + (jj&7) + (jj>>3)*64 -> each XCD sees
// wdw in {xcd*8 .. xcd*8+7} only (comb L2-resident).
// LDS (ushort units), total 25600 ush = 51,200 B:
//   xb     [0,16384)      : x bf16 [64][256], 16B-chunk j^(n&7) swizzle
//   vtw[w] 16384 + w*2304 : [32][72] v transposed (per wave, reused h0->h1)
//   P[w]   w*4608         : [64][72] FULL, wave-private. P[3] tail overlaps
//          vtw[0] only — dead (all vf loaded pre-barrier).
//   ao     [0,16896)      : [64][264] — aliases xb/P after barrier 2
// Barriers: stage-x | GEMMs done | PV done | ao stored.
__global__ __launch_bounds__(256, 2) void k_mono(
        const ushort* __restrict__ qwb, const float* __restrict__ x,
        const float* __restrict__ qb, const float* __restrict__ comb,
        const ushort* __restrict__ pwb, const float* __restrict__ pb,
        float* __restrict__ out) {
    __shared__ ushort smem[25600];   // 51,200 B
    ushort* xb = smem;

    const int t = threadIdx.x;
    const int w = t >> 6, l = t & 63;
    const int g = l >> 4, li = l & 15;
    // XCD-bijective remap (hi = jj>>3 in [0,64), mid = xcd, lo = jj&7)
    const int bid = blockIdx.x;
    const int xcd = bid & 7, jj_ = bid >> 3;
    const int blk = xcd * 8 + (jj_ & 7) + ((jj_ >> 3) << 6);
    const int wdw = blk & 63;

    ushort* vtw = smem + 16384 + w * 2304;   // [32][72]
    ushort* P   = smem + w * 4608;           // [64][72] full, wave-private
    ushort* ao  = smem;                      // [64][264]

    const floatx4 zf = {0.f, 0.f, 0.f, 0.f};
    const float scale = 0.17677669529663687f;  // 32^-0.5

    // ---- phase 0: stage x -> xb (bf16, 16B-chunk j^(n&7) swizzle) ----
#pragma unroll
    for (int rep = 0; rep < 2; ++rep) {
        const int n = (t >> 3) + rep * 32;
        const int seg = t & 7;
        if (n < 49) {
            const float* src = x + ((size_t)blk * 49 + n) * 256 + seg * 32;
#pragma unroll
            for (int c4 = 0; c4 < 4; ++c4) {
                const float4 a  = *(const float4*)(src + c4 * 8);
                const float4 b2 = *(const float4*)(src + c4 * 8 + 4);
                uint4 u;
                u.x = cvtpk(a.x, a.y);  u.y = cvtpk(a.z, a.w);
                u.z = cvtpk(b2.x, b2.y); u.w = cvtpk(b2.z, b2.w);
                const int j = seg * 4 + c4;
                *(uint4*)(xb + n * 256 + ((j ^ (n & 7)) * 8)) = u;
            }
        } else {
            const uint4 z = {0u, 0u, 0u, 0u};
#pragma unroll
            for (int c4 = 0; c4 < 4; ++c4) {
                const int j = seg * 4 + c4;
                *(uint4*)(xb + n * 256 + ((j ^ (n & 7)) * 8)) = z;
            }
        }
    }
    __syncthreads();

    // one GEMM pass: 2 c-tiles (W rows BASE, BASE+16), acc[2][4].
    // acc[ct][nt] lane map: c = BASE + ct*16 + g*4 + r, n = nt*16 + li.
    floatx4 acc[2][4];
#define GEMM_PASS(BASE)                                                       \
    {                                                                         \
        _Pragma("unroll")                                                     \
        for (int i = 0; i < 2; ++i)                                           \
            _Pragma("unroll")                                                 \
            for (int jj = 0; jj < 4; ++jj) acc[i][jj] = zf;                   \
        _Pragma("unroll")                                                     \
        for (int kt = 0; kt < 8; ++kt) {                                      \
            const short8 af0 = *(const short8*)(qwb +                         \
                (size_t)((BASE) + li) * 256 + kt * 32 + g * 8);               \
            const short8 af1 = *(const short8*)(qwb +                         \
                (size_t)((BASE) + 16 + li) * 256 + kt * 32 + g * 8);          \
            _Pragma("unroll")                                                 \
            for (int nt = 0; nt < 4; ++nt) {                                  \
                const short8 bx = *(const short8*)(xb +                       \
                    (nt * 16 + li) * 256 + (((kt * 4 + g) ^ (li & 7)) * 8));  \
                acc[0][nt] = __builtin_amdgcn_mfma_f32_16x16x32_bf16(         \
                    af0, bx, acc[0][nt], 0, 0, 0);                            \
                acc[1][nt] = __builtin_amdgcn_mfma_f32_16x16x32_bf16(         \
                    af1, bx, acc[1][nt], 0, 0, 0);                            \
            }                                                                 \
        }                                                                     \
    }

    // acc (+bias) -> B-operand frag via in-register transpose (S10/S12-proven)
#define XPOSE_QK(CBASE, OUTF)                                                 \
    {                                                                         \
        uint2 u2[2][4];                                                       \
        _Pragma("unroll")                                                     \
        for (int ct = 0; ct < 2; ++ct) {                                      \
            const float4 b4 = *(const float4*)(qb + (CBASE) + ct * 16 + g * 4);\
            _Pragma("unroll")                                                 \
            for (int nt = 0; nt < 4; ++nt) {                                  \
                u2[ct][nt].x = cvtpk(acc[ct][nt][0] + b4.x,                   \
                                     acc[ct][nt][1] + b4.y);                  \
                u2[ct][nt].y = cvtpk(acc[ct][nt][2] + b4.z,                   \
                                     acc[ct][nt][3] + b4.w);                  \
            }                                                                 \
        }                                                                     \
        const int src0 = li + (g & 1) * 32, src1 = src0 + 16;                 \
        _Pragma("unroll")                                                     \
        for (int mt = 0; mt < 4; ++mt) {                                      \
            const uint2 a0 = shfl2(u2[0][mt], src0);                          \
            const uint2 a1 = shfl2(u2[0][mt], src1);                          \
            const uint2 b0 = shfl2(u2[1][mt], src0);                          \
            const uint2 b1 = shfl2(u2[1][mt], src1);                          \
            union { short8 s; uint32_t q[4]; } cv;                            \
            cv.q[0] = (g < 2) ? a0.x : b0.x;                                  \
            cv.q[1] = (g < 2) ? a0.y : b0.y;                                  \
            cv.q[2] = (g < 2) ? a1.x : b1.x;                                  \
            cv.q[3] = (g < 2) ? a1.y : b1.y;                                  \
            OUTF[mt] = cv.s;                                                  \
        }                                                                     \
    }

    // ---- GEMM passes for both heads (xb live throughout) ----
    short8 qf[2][4], kf[2][4], vf[2][2][2];
#pragma unroll
    for (int hh = 0; hh < 2; ++hh) {
        const int hd = w * 2 + hh;
        GEMM_PASS(hd * 32)
        XPOSE_QK(hd * 32, qf[hh])
        GEMM_PASS(256 + hd * 32)
        XPOSE_QK(256 + hd * 32, kf[hh])
        GEMM_PASS(512 + hd * 32)
        // V epilogue -> vtw (transposed [dd][n]), then frags (region reused)
#pragma unroll
        for (int ct = 0; ct < 2; ++ct) {
            const int dd0 = ct * 16 + g * 4;
            const float4 b4 = *(const float4*)(qb + 512 + hd * 32 + dd0);
#pragma unroll
            for (int nt = 0; nt < 4; ++nt) {
                const int n = nt * 16 + li;
                vtw[(dd0 + 0) * 72 + n] = f2bf(acc[ct][nt][0] + b4.x);
                vtw[(dd0 + 1) * 72 + n] = f2bf(acc[ct][nt][1] + b4.y);
                vtw[(dd0 + 2) * 72 + n] = f2bf(acc[ct][nt][2] + b4.z);
                vtw[(dd0 + 3) * 72 + n] = f2bf(acc[ct][nt][3] + b4.w);
            }
        }
#pragma unroll
        for (int ks = 0; ks < 2; ++ks)
#pragma unroll
            for (int nt = 0; nt < 2; ++nt)
                vf[hh][ks][nt] = *(const short8*)(vtw + (nt * 16 + li) * 72 +
                                                  ks * 32 + g * 8);
    }
    __syncthreads();   // xb + all vtw dead: P (aliasing them) may be written

    // ---- attention per head (S12/S15 math verbatim) ----
    floatx4 oac[2][4][2];
#pragma unroll
    for (int hh = 0; hh < 2; ++hh) {
        const int hd = w * 2 + hh;
        const float* cw = comb + (size_t)(wdw * 8 + hd) * 4096;
#pragma unroll
        for (int bq = 0; bq < 4; ++bq) {
            floatx4 sac[4];
#pragma unroll
            for (int ak = 0; ak < 4; ++ak)
                sac[ak] = __builtin_amdgcn_mfma_f32_16x16x32_bf16(
                    kf[hh][ak], qf[hh][bq], zf, 0, 0, 0);

            const int n = bq * 16 + li;
            const float* cr = cw + n * 64 + g * 4;
            const float4 c0 = *(const float4*)(cr);
            const float4 c1 = *(const float4*)(cr + 16);
            const float4 c2 = *(const float4*)(cr + 32);
            const float c3x = cr[48];
            float v[12];
            v[0]  = sac[0][0] * scale + c0.x;
            v[1]  = sac[0][1] * scale + c0.y;
            v[2]  = sac[0][2] * scale + c0.z;
            v[3]  = sac[0][3] * scale + c0.w;
            v[4]  = sac[1][0] * scale + c1.x;
            v[5]  = sac[1][1] * scale + c1.y;
            v[6]  = sac[1][2] * scale + c1.z;
            v[7]  = sac[1][3] * scale + c1.w;
            v[8]  = sac[2][0] * scale + c2.x;
            v[9]  = sac[2][1] * scale + c2.y;
            v[10] = sac[2][2] * scale + c2.z;
            v[11] = sac[2][3] * scale + c2.w;
            const float v48 = (g == 0) ? sac[3][0] * scale + c3x : -3.0e38f;
            float mx = fmaxf(fmaxf(fmaxf(v[0], v[1]), fmaxf(v[2], v[3])),
                             fmaxf(fmaxf(v[4], v[5]), fmaxf(v[6], v[7])));
            mx = fmaxf(mx, fmaxf(fmaxf(v[8], v[9]), fmaxf(v[10], v[11])));
            mx = fmaxf(mx, v48);
            mx = fmaxf(mx, __shfl_xor(mx, 16, 64));
            mx = fmaxf(mx, __shfl_xor(mx, 32, 64));
            float e[12], s = 0.f;
#pragma unroll
            for (int i = 0; i < 12; ++i) { e[i] = __expf(v[i] - mx); s += e[i]; }
            const float e48 = __expf(v48 - mx);   // exactly 0 for g>0
            s += e48;
            s += __shfl_xor(s, 16, 64);
            s += __shfl_xor(s, 32, 64);
            const float inv = 1.0f / s;
            uint2 pk;
#pragma unroll
            for (int a = 0; a < 3; ++a) {
                pk.x = cvtpk(e[a * 4 + 0] * inv, e[a * 4 + 1] * inv);
                pk.y = cvtpk(e[a * 4 + 2] * inv, e[a * 4 + 3] * inv);
                *(uint2*)(P + n * 72 + a * 16 + g * 4) = pk;
            }
            pk.x = cvtpk(e48 * inv, 0.f);
            pk.y = 0u;
            *(uint2*)(P + n * 72 + 48 + g * 4) = pk;   // cols 49..63 exact 0
        }

        // O = P V (wave-private; hh=0's PV completes before hh=1 rewrites P)
#pragma unroll
        for (int mt = 0; mt < 4; ++mt)
#pragma unroll
            for (int nt = 0; nt < 2; ++nt) oac[hh][mt][nt] = zf;
#pragma unroll
        for (int ks = 0; ks < 2; ++ks)
#pragma unroll
            for (int mt = 0; mt < 4; ++mt) {
                const short8 pf = *(const short8*)(P + (mt * 16 + li) * 72 +
                                                   ks * 32 + g * 8);
                oac[hh][mt][0] = __builtin_amdgcn_mfma_f32_16x16x32_bf16(
                    pf, vf[hh][ks][0], oac[hh][mt][0], 0, 0, 0);
                oac[hh][mt][1] = __builtin_amdgcn_mfma_f32_16x16x32_bf16(
                    pf, vf[hh][ks][1], oac[hh][mt][1], 0, 0, 0);
            }
    }

    __syncthreads();   // all waves done with P: ao may overwrite

    // ---- store O into ao[n][hd*32+dd]; zero pad rows (wave: 64 cols) ----
#pragma unroll
    for (int hh = 0; hh < 2; ++hh) {
        const int hd = w * 2 + hh;
#pragma unroll
        for (int mt = 0; mt < 4; ++mt)
#pragma unroll
            for (int rr = 0; rr < 4; ++rr) {
                const int n = mt * 16 + g * 4 + rr;
                if (n < 49) {
#pragma unroll
                    for (int nt = 0; nt < 2; ++nt)
                        ao[n * 264 + hd * 32 + nt * 16 + li] =
                            f2bf(oac[hh][mt][nt][rr]);
                }
            }
    }
    for (int idx = l; idx < 480; idx += 64) {
        const int n = 49 + (idx >> 5);
        const int du = idx & 31;
        *(uint32_t*)(ao + n * 264 + w * 64 + du * 2) = 0u;
    }
    __syncthreads();

    // ---- proj: wave w covers cols w*64..w*64+63; pacc[4][4] ----
    floatx4 pacc[4][4];
#pragma unroll
    for (int mt = 0; mt < 4; ++mt)
#pragma unroll
        for (int nt = 0; nt < 4; ++nt) pacc[mt][nt] = zf;
#pragma unroll
    for (int kt = 0; kt < 8; ++kt) {
        short8 afr[4], wfr[4];
#pragma unroll
        for (int mt = 0; mt < 4; ++mt)
            afr[mt] = *(const short8*)(ao + (mt * 16 + li) * 264 + kt * 32 + g * 8);
#pragma unroll
        for (int nt = 0; nt < 4; ++nt)
            wfr[nt] = *(const short8*)(pwb +
                (size_t)(w * 64 + nt * 16 + li) * 256 + kt * 32 + g * 8);
#pragma unroll
        for (int mt = 0; mt < 4; ++mt)
#pragma unroll
            for (int nt = 0; nt < 4; ++nt)
                pacc[mt][nt] = __builtin_amdgcn_mfma_f32_16x16x32_bf16(
                    afr[mt], wfr[nt], pacc[mt][nt], 0, 0, 0);
    }

    float* og = out + (size_t)blk * 49 * 256;
#pragma unroll
    for (int nt = 0; nt < 4; ++nt) {
        const int c = w * 64 + nt * 16 + li;
        const float bias = pb[c];
#pragma unroll
        for (int mt = 0; mt < 4; ++mt)
#pragma unroll
            for (int r = 0; r < 4; ++r) {
                const int n = mt * 16 + g * 4 + r;
                if (n < 49) og[(size_t)n * 256 + c] = pacc[mt][nt][r] + bias;
            }
    }
#undef GEMM_PASS
#undef XPOSE_QK
}

// ---------------------------------------------------------------------------
extern "C" void kernel_launch(void* const* d_in, const int* in_sizes, int n_in,
                              void* d_out, int out_size, void* d_ws, size_t ws_size,
                              hipStream_t stream) {
    const float* x      = (const float*)d_in[0];
    const float* mask   = (const float*)d_in[1];
    const int*   rel    = (const int*)d_in[2];
    const float* qkv_w  = (const float*)d_in[3];
    const float* qkv_b  = (const float*)d_in[4];
    const float* proj_w = (const float*)d_in[5];
    const float* proj_b = (const float*)d_in[6];
    const float* bt     = (const float*)d_in[7];
    float* out = (float*)d_out;

    // ws layout (bytes); total = 8,912,896 (~8.5 MiB)
    char* ws = (char*)d_ws;
    ushort* qwb  = (ushort*)(ws);                  // 768*256 bf16   (393216 B)
    ushort* pwb  = (ushort*)(ws + 393216);         // 256*256 bf16   (131072 B)
    float*  comb = (float*) (ws + 524288);         // 512*64*64 f32  (8388608 B)
    (void)ws_size; (void)in_sizes; (void)n_in; (void)out_size;

    k_cvt_w<<<dim3(1024), dim3(256), 0, stream>>>(qkv_w, proj_w, qwb, pwb);
    k_comb <<<dim3(512),  dim3(256), 0, stream>>>(mask, rel, bt, comb);
    k_mono <<<dim3(4096), dim3(256), 0, stream>>>(qwb, x, qkv_b, comb, pwb,
                                                  proj_b, out);
}

// Round 18
// 393.361 us; speedup vs baseline: 1.2710x; 1.0017x over previous
//
#include <hip/hip_runtime.h>
#include <cstdint>

// ---------------------------------------------------------------------------
// WindowAttention (Swin): B_WIN=4096 windows, N=49 tokens, DIM=256, HEADS=8,
// head_dim=32, NW=64 masks.
// S18 = S17 (round-17, PASSING, 394.0us) + exactly ONE delta:
//   GEMM_PASS batch-hoists all 16 af (W-fragment) global loads into
//   registers BEFORE the MFMA loop (afp[8][2], static indices). Pure
//   load-scheduling change — same addresses, same values, same math.
//   Mechanism: exposes all 16 L2 loads concurrently instead of ~2-at-a-time,
//   removing ~2K cy of serialized latency per pass (6 passes/wave).
// ---------------------------------------------------------------------------

typedef __attribute__((ext_vector_type(8))) short short8;   // bf16x8 frag
typedef __attribute__((ext_vector_type(4))) float floatx4;  // fp32x4 acc frag

__device__ __forceinline__ ushort f2bf(float f) {
    uint32_t u = __float_as_uint(f);
    u += 0x7FFFu + ((u >> 16) & 1u);   // RNE
    return (ushort)(u >> 16);
}

__device__ __forceinline__ uint32_t cvtpk(float lo, float hi) {
    uint32_t r;
    asm("v_cvt_pk_bf16_f32 %0, %1, %2" : "=v"(r) : "v"(lo), "v"(hi));
    return r;
}

__device__ __forceinline__ uint2 shfl2(uint2 v, int lane) {
    uint2 r;
    r.x = (uint32_t)__shfl((int)v.x, lane, 64);
    r.y = (uint32_t)__shfl((int)v.y, lane, 64);
    return r;
}

// ---------------------------------------------------------------- kernel 0b
__global__ __launch_bounds__(256) void k_cvt_w(const float* __restrict__ qw,
                                               const float* __restrict__ pw,
                                               ushort* __restrict__ qwb,
                                               ushort* __restrict__ pwb) {
    int i = blockIdx.x * 256 + threadIdx.x;
    if (i < 196608) qwb[i] = f2bf(qw[i]);
    else            pwb[i - 196608] = f2bf(pw[i - 196608]);
}

// ---------------------------------------------------------------- kernel 0c
// comb[wh][n][m] padded to stride 64: comb[wh*4096 + n*64 + m], m-pad zeroed.
__global__ __launch_bounds__(256) void k_comb(const float* __restrict__ mask,
                                              const int* __restrict__ rel,
                                              const float* __restrict__ bt,
                                              float* __restrict__ comb) {
    const int wh = blockIdx.x;
    const int w = wh >> 3, h = wh & 7;
    const float* mw = mask + (size_t)w * 2401;
    float* out = comb + (size_t)wh * 4096;
    for (int e = threadIdx.x; e < 49 * 64; e += 256) {
        const int n = e >> 6, m = e & 63;
        out[e] = (m < 49) ? mw[n * 49 + m] + bt[rel[n * 49 + m] * 8 + h] : 0.0f;
    }
}

// ---------------------------------------------------------------- kernel 1
// Monolithic per-window kernel. 256 thr (4 waves), wave w = heads 2w, 2w+1.
// XCD-bijective remap: blk = xcd*8 + (jj&7) + (jj>>3)*64 -> each XCD sees
// wdw in {xcd*8 .. xcd*8+7} only (comb L2-resident).
// LDS (ushort units), total 25600 ush = 51,200 B:
//   xb     [0,16384)      : x bf16 [64][256], 16B-chunk j^(n&7) swizzle
//   vtw[w] 16384 + w*2304 : [32][72] v transposed (per wave, reused h0->h1)
//   P[w]   w*4608         : [64][72] FULL, wave-private. P[3] tail overlaps
//          vtw[0] only — dead (all vf loaded pre-barrier).
//   ao     [0,16896)      : [64][264] — aliases xb/P after barrier 2
// Barriers: stage-x | GEMMs done | PV done | ao stored.
__global__ __launch_bounds__(256, 2) void k_mono(
        const ushort* __restrict__ qwb, const float* __restrict__ x,
        const float* __restrict__ qb, const float* __restrict__ comb,
        const ushort* __restrict__ pwb, const float* __restrict__ pb,
        float* __restrict__ out) {
    __shared__ ushort smem[25600];   // 51,200 B
    ushort* xb = smem;

    const int t = threadIdx.x;
    const int w = t >> 6, l = t & 63;
    const int g = l >> 4, li = l & 15;
    // XCD-bijective remap (hi = jj>>3 in [0,64), mid = xcd, lo = jj&7)
    const int bid = blockIdx.x;
    const int xcd = bid & 7, jj_ = bid >> 3;
    const int blk = xcd * 8 + (jj_ & 7) + ((jj_ >> 3) << 6);
    const int wdw = blk & 63;

    ushort* vtw = smem + 16384 + w * 2304;   // [32][72]
    ushort* P   = smem + w * 4608;           // [64][72] full, wave-private
    ushort* ao  = smem;                      // [64][264]

    const floatx4 zf = {0.f, 0.f, 0.f, 0.f};
    const float scale = 0.17677669529663687f;  // 32^-0.5

    // ---- phase 0: stage x -> xb (bf16, 16B-chunk j^(n&7) swizzle) ----
#pragma unroll
    for (int rep = 0; rep < 2; ++rep) {
        const int n = (t >> 3) + rep * 32;
        const int seg = t & 7;
        if (n < 49) {
            const float* src = x + ((size_t)blk * 49 + n) * 256 + seg * 32;
#pragma unroll
            for (int c4 = 0; c4 < 4; ++c4) {
                const float4 a  = *(const float4*)(src + c4 * 8);
                const float4 b2 = *(const float4*)(src + c4 * 8 + 4);
                uint4 u;
                u.x = cvtpk(a.x, a.y);  u.y = cvtpk(a.z, a.w);
                u.z = cvtpk(b2.x, b2.y); u.w = cvtpk(b2.z, b2.w);
                const int j = seg * 4 + c4;
                *(uint4*)(xb + n * 256 + ((j ^ (n & 7)) * 8)) = u;
            }
        } else {
            const uint4 z = {0u, 0u, 0u, 0u};
#pragma unroll
            for (int c4 = 0; c4 < 4; ++c4) {
                const int j = seg * 4 + c4;
                *(uint4*)(xb + n * 256 + ((j ^ (n & 7)) * 8)) = z;
            }
        }
    }
    __syncthreads();

    // one GEMM pass: 2 c-tiles (W rows BASE, BASE+16), acc[2][4].
    // acc[ct][nt] lane map: c = BASE + ct*16 + g*4 + r, n = nt*16 + li.
    // S18: all 16 af loads batch-hoisted into afp[8][2] (static indices ->
    // registers) so the L2 latency is paid once per pass, not per kt.
    floatx4 acc[2][4];
#define GEMM_PASS(BASE)                                                       \
    {                                                                         \
        short8 afp[8][2];                                                     \
        _Pragma("unroll")                                                     \
        for (int kt = 0; kt < 8; ++kt) {                                      \
            afp[kt][0] = *(const short8*)(qwb +                               \
                (size_t)((BASE) + li) * 256 + kt * 32 + g * 8);               \
            afp[kt][1] = *(const short8*)(qwb +                               \
                (size_t)((BASE) + 16 + li) * 256 + kt * 32 + g * 8);          \
        }                                                                     \
        _Pragma("unroll")                                                     \
        for (int i = 0; i < 2; ++i)                                           \
            _Pragma("unroll")                                                 \
            for (int jj = 0; jj < 4; ++jj) acc[i][jj] = zf;                   \
        _Pragma("unroll")                                                     \
        for (int kt = 0; kt < 8; ++kt) {                                      \
            _Pragma("unroll")                                                 \
            for (int nt = 0; nt < 4; ++nt) {                                  \
                const short8 bx = *(const short8*)(xb +                       \
                    (nt * 16 + li) * 256 + (((kt * 4 + g) ^ (li & 7)) * 8));  \
                acc[0][nt] = __builtin_amdgcn_mfma_f32_16x16x32_bf16(         \
                    afp[kt][0], bx, acc[0][nt], 0, 0, 0);                     \
                acc[1][nt] = __builtin_amdgcn_mfma_f32_16x16x32_bf16(         \
                    afp[kt][1], bx, acc[1][nt], 0, 0, 0);                     \
            }                                                                 \
        }                                                                     \
    }

    // acc (+bias) -> B-operand frag via in-register transpose (S10/S12-proven)
#define XPOSE_QK(CBASE, OUTF)                                                 \
    {                                                                         \
        uint2 u2[2][4];                                                       \
        _Pragma("unroll")                                                     \
        for (int ct = 0; ct < 2; ++ct) {                                      \
            const float4 b4 = *(const float4*)(qb + (CBASE) + ct * 16 + g * 4);\
            _Pragma("unroll")                                                 \
            for (int nt = 0; nt < 4; ++nt) {                                  \
                u2[ct][nt].x = cvtpk(acc[ct][nt][0] + b4.x,                   \
                                     acc[ct][nt][1] + b4.y);                  \
                u2[ct][nt].y = cvtpk(acc[ct][nt][2] + b4.z,                   \
                                     acc[ct][nt][3] + b4.w);                  \
            }                                                                 \
        }                                                                     \
        const int src0 = li + (g & 1) * 32, src1 = src0 + 16;                 \
        _Pragma("unroll")                                                     \
        for (int mt = 0; mt < 4; ++mt) {                                      \
            const uint2 a0 = shfl2(u2[0][mt], src0);                          \
            const uint2 a1 = shfl2(u2[0][mt], src1);                          \
            const uint2 b0 = shfl2(u2[1][mt], src0);                          \
            const uint2 b1 = shfl2(u2[1][mt], src1);                          \
            union { short8 s; uint32_t q[4]; } cv;                            \
            cv.q[0] = (g < 2) ? a0.x : b0.x;                                  \
            cv.q[1] = (g < 2) ? a0.y : b0.y;                                  \
            cv.q[2] = (g < 2) ? a1.x : b1.x;                                  \
            cv.q[3] = (g < 2) ? a1.y : b1.y;                                  \
            OUTF[mt] = cv.s;                                                  \
        }                                                                     \
    }

    // ---- GEMM passes for both heads (xb live throughout) ----
    short8 qf[2][4], kf[2][4], vf[2][2][2];
#pragma unroll
    for (int hh = 0; hh < 2; ++hh) {
        const int hd = w * 2 + hh;
        GEMM_PASS(hd * 32)
        XPOSE_QK(hd * 32, qf[hh])
        GEMM_PASS(256 + hd * 32)
        XPOSE_QK(256 + hd * 32, kf[hh])
        GEMM_PASS(512 + hd * 32)
        // V epilogue -> vtw (transposed [dd][n]), then frags (region reused)
#pragma unroll
        for (int ct = 0; ct < 2; ++ct) {
            const int dd0 = ct * 16 + g * 4;
            const float4 b4 = *(const float4*)(qb + 512 + hd * 32 + dd0);
#pragma unroll
            for (int nt = 0; nt < 4; ++nt) {
                const int n = nt * 16 + li;
                vtw[(dd0 + 0) * 72 + n] = f2bf(acc[ct][nt][0] + b4.x);
                vtw[(dd0 + 1) * 72 + n] = f2bf(acc[ct][nt][1] + b4.y);
                vtw[(dd0 + 2) * 72 + n] = f2bf(acc[ct][nt][2] + b4.z);
                vtw[(dd0 + 3) * 72 + n] = f2bf(acc[ct][nt][3] + b4.w);
            }
        }
#pragma unroll
        for (int ks = 0; ks < 2; ++ks)
#pragma unroll
            for (int nt = 0; nt < 2; ++nt)
                vf[hh][ks][nt] = *(const short8*)(vtw + (nt * 16 + li) * 72 +
                                                  ks * 32 + g * 8);
    }
    __syncthreads();   // xb + all vtw dead: P (aliasing them) may be written

    // ---- attention per head (S12/S15 math verbatim) ----
    floatx4 oac[2][4][2];
#pragma unroll
    for (int hh = 0; hh < 2; ++hh) {
        const int hd = w * 2 + hh;
        const float* cw = comb + (size_t)(wdw * 8 + hd) * 4096;
#pragma unroll
        for (int bq = 0; bq < 4; ++bq) {
            floatx4 sac[4];
#pragma unroll
            for (int ak = 0; ak < 4; ++ak)
                sac[ak] = __builtin_amdgcn_mfma_f32_16x16x32_bf16(
                    kf[hh][ak], qf[hh][bq], zf, 0, 0, 0);

            const int n = bq * 16 + li;
            const float* cr = cw + n * 64 + g * 4;
            const float4 c0 = *(const float4*)(cr);
            const float4 c1 = *(const float4*)(cr + 16);
            const float4 c2 = *(const float4*)(cr + 32);
            const float c3x = cr[48];
            float v[12];
            v[0]  = sac[0][0] * scale + c0.x;
            v[1]  = sac[0][1] * scale + c0.y;
            v[2]  = sac[0][2] * scale + c0.z;
            v[3]  = sac[0][3] * scale + c0.w;
            v[4]  = sac[1][0] * scale + c1.x;
            v[5]  = sac[1][1] * scale + c1.y;
            v[6]  = sac[1][2] * scale + c1.z;
            v[7]  = sac[1][3] * scale + c1.w;
            v[8]  = sac[2][0] * scale + c2.x;
            v[9]  = sac[2][1] * scale + c2.y;
            v[10] = sac[2][2] * scale + c2.z;
            v[11] = sac[2][3] * scale + c2.w;
            const float v48 = (g == 0) ? sac[3][0] * scale + c3x : -3.0e38f;
            float mx = fmaxf(fmaxf(fmaxf(v[0], v[1]), fmaxf(v[2], v[3])),
                             fmaxf(fmaxf(v[4], v[5]), fmaxf(v[6], v[7])));
            mx = fmaxf(mx, fmaxf(fmaxf(v[8], v[9]), fmaxf(v[10], v[11])));
            mx = fmaxf(mx, v48);
            mx = fmaxf(mx, __shfl_xor(mx, 16, 64));
            mx = fmaxf(mx, __shfl_xor(mx, 32, 64));
            float e[12], s = 0.f;
#pragma unroll
            for (int i = 0; i < 12; ++i) { e[i] = __expf(v[i] - mx); s += e[i]; }
            const float e48 = __expf(v48 - mx);   // exactly 0 for g>0
            s += e48;
            s += __shfl_xor(s, 16, 64);
            s += __shfl_xor(s, 32, 64);
            const float inv = 1.0f / s;
            uint2 pk;
#pragma unroll
            for (int a = 0; a < 3; ++a) {
                pk.x = cvtpk(e[a * 4 + 0] * inv, e[a * 4 + 1] * inv);
                pk.y = cvtpk(e[a * 4 + 2] * inv, e[a * 4 + 3] * inv);
                *(uint2*)(P + n * 72 + a * 16 + g * 4) = pk;
            }
            pk.x = cvtpk(e48 * inv, 0.f);
            pk.y = 0u;
            *(uint2*)(P + n * 72 + 48 + g * 4) = pk;   // cols 49..63 exact 0
        }

        // O = P V (wave-private; hh=0's PV completes before hh=1 rewrites P)
#pragma unroll
        for (int mt = 0; mt < 4; ++mt)
#pragma unroll
            for (int nt = 0; nt < 2; ++nt) oac[hh][mt][nt] = zf;
#pragma unroll
        for (int ks = 0; ks < 2; ++ks)
#pragma unroll
            for (int mt = 0; mt < 4; ++mt) {
                const short8 pf = *(const short8*)(P + (mt * 16 + li) * 72 +
                                                   ks * 32 + g * 8);
                oac[hh][mt][0] = __builtin_amdgcn_mfma_f32_16x16x32_bf16(
                    pf, vf[hh][ks][0], oac[hh][mt][0], 0, 0, 0);
                oac[hh][mt][1] = __builtin_amdgcn_mfma_f32_16x16x32_bf16(
                    pf, vf[hh][ks][1], oac[hh][mt][1], 0, 0, 0);
            }
    }

    __syncthreads();   // all waves done with P: ao may overwrite

    // ---- store O into ao[n][hd*32+dd]; zero pad rows (wave: 64 cols) ----
#pragma unroll
    for (int hh = 0; hh < 2; ++hh) {
        const int hd = w * 2 + hh;
#pragma unroll
        for (int mt = 0; mt < 4; ++mt)
#pragma unroll
            for (int rr = 0; rr < 4; ++rr) {
                const int n = mt * 16 + g * 4 + rr;
                if (n < 49) {
#pragma unroll
                    for (int nt = 0; nt < 2; ++nt)
                        ao[n * 264 + hd * 32 + nt * 16 + li] =
                            f2bf(oac[hh][mt][nt][rr]);
                }
            }
    }
    for (int idx = l; idx < 480; idx += 64) {
        const int n = 49 + (idx >> 5);
        const int du = idx & 31;
        *(uint32_t*)(ao + n * 264 + w * 64 + du * 2) = 0u;
    }
    __syncthreads();

    // ---- proj: wave w covers cols w*64..w*64+63; pacc[4][4] ----
    floatx4 pacc[4][4];
#pragma unroll
    for (int mt = 0; mt < 4; ++mt)
#pragma unroll
        for (int nt = 0; nt < 4; ++nt) pacc[mt][nt] = zf;
#pragma unroll
    for (int kt = 0; kt < 8; ++kt) {
        short8 afr[4], wfr[4];
#pragma unroll
        for (int mt = 0; mt < 4; ++mt)
            afr[mt] = *(const short8*)(ao + (mt * 16 + li) * 264 + kt * 32 + g * 8);
#pragma unroll
        for (int nt = 0; nt < 4; ++nt)
            wfr[nt] = *(const short8*)(pwb +
                (size_t)(w * 64 + nt * 16 + li) * 256 + kt * 32 + g * 8);
#pragma unroll
        for (int mt = 0; mt < 4; ++mt)
#pragma unroll
            for (int nt = 0; nt < 4; ++nt)
                pacc[mt][nt] = __builtin_amdgcn_mfma_f32_16x16x32_bf16(
                    afr[mt], wfr[nt], pacc[mt][nt], 0, 0, 0);
    }

    float* og = out + (size_t)blk * 49 * 256;
#pragma unroll
    for (int nt = 0; nt < 4; ++nt) {
        const int c = w * 64 + nt * 16 + li;
        const float bias = pb[c];
#pragma unroll
        for (int mt = 0; mt < 4; ++mt)
#pragma unroll
            for (int r = 0; r < 4; ++r) {
                const int n = mt * 16 + g * 4 + r;
                if (n < 49) og[(size_t)n * 256 + c] = pacc[mt][nt][r] + bias;
            }
    }
#undef GEMM_PASS
#undef XPOSE_QK
}

// ---------------------------------------------------------------------------
extern "C" void kernel_launch(void* const* d_in, const int* in_sizes, int n_in,
                              void* d_out, int out_size, void* d_ws, size_t ws_size,
                              hipStream_t stream) {
    const float* x      = (const float*)d_in[0];
    const float* mask   = (const float*)d_in[1];
    const int*   rel    = (const int*)d_in[2];
    const float* qkv_w  = (const float*)d_in[3];
    const float* qkv_b  = (const float*)d_in[4];
    const float* proj_w = (const float*)d_in[5];
    const float* proj_b = (const float*)d_in[6];
    const float* bt     = (const float*)d_in[7];
    float* out = (float*)d_out;

    // ws layout (bytes); total = 8,912,896 (~8.5 MiB)
    char* ws = (char*)d_ws;
    ushort* qwb  = (ushort*)(ws);                  // 768*256 bf16   (393216 B)
    ushort* pwb  = (ushort*)(ws + 393216);         // 256*256 bf16   (131072 B)
    float*  comb = (float*) (ws + 524288);         // 512*64*64 f32  (8388608 B)
    (void)ws_size; (void)in_sizes; (void)n_in; (void)out_size;

    k_cvt_w<<<dim3(1024), dim3(256), 0, stream>>>(qkv_w, proj_w, qwb, pwb);
    k_comb <<<dim3(512),  dim3(256), 0, stream>>>(mask, rel, bt, comb);
    k_mono <<<dim3(4096), dim3(256), 0, stream>>>(qwb, x, qkv_b, comb, pwb,
                                                  proj_b, out);
}

// Round 19
// 371.653 us; speedup vs baseline: 1.3453x; 1.0584x over previous
//
#include <hip/hip_runtime.h>
#include <cstdint>

// ---------------------------------------------------------------------------
// WindowAttention (Swin): B_WIN=4096 windows, N=49 tokens, DIM=256, HEADS=8,
// head_dim=32, NW=64 masks.
// S19 = S18 (round-18, PASSING, 393.4us) + exactly ONE delta:
//   __builtin_amdgcn_sched_barrier(0) between the afp batch-load loop and
//   the MFMA loop in GEMM_PASS. S18's source-level hoist was folded back by
//   the scheduler (VGPR_Count stayed 128); the fence pins all 16 qwb loads
//   ahead of the MFMAs so their L2 latency is paid once per pass.
//   Verification signature: VGPR_Count should rise to ~190.
// ---------------------------------------------------------------------------

typedef __attribute__((ext_vector_type(8))) short short8;   // bf16x8 frag
typedef __attribute__((ext_vector_type(4))) float floatx4;  // fp32x4 acc frag

__device__ __forceinline__ ushort f2bf(float f) {
    uint32_t u = __float_as_uint(f);
    u += 0x7FFFu + ((u >> 16) & 1u);   // RNE
    return (ushort)(u >> 16);
}

__device__ __forceinline__ uint32_t cvtpk(float lo, float hi) {
    uint32_t r;
    asm("v_cvt_pk_bf16_f32 %0, %1, %2" : "=v"(r) : "v"(lo), "v"(hi));
    return r;
}

__device__ __forceinline__ uint2 shfl2(uint2 v, int lane) {
    uint2 r;
    r.x = (uint32_t)__shfl((int)v.x, lane, 64);
    r.y = (uint32_t)__shfl((int)v.y, lane, 64);
    return r;
}

// ---------------------------------------------------------------- kernel 0b
__global__ __launch_bounds__(256) void k_cvt_w(const float* __restrict__ qw,
                                               const float* __restrict__ pw,
                                               ushort* __restrict__ qwb,
                                               ushort* __restrict__ pwb) {
    int i = blockIdx.x * 256 + threadIdx.x;
    if (i < 196608) qwb[i] = f2bf(qw[i]);
    else            pwb[i - 196608] = f2bf(pw[i - 196608]);
}

// ---------------------------------------------------------------- kernel 0c
// comb[wh][n][m] padded to stride 64: comb[wh*4096 + n*64 + m], m-pad zeroed.
__global__ __launch_bounds__(256) void k_comb(const float* __restrict__ mask,
                                              const int* __restrict__ rel,
                                              const float* __restrict__ bt,
                                              float* __restrict__ comb) {
    const int wh = blockIdx.x;
    const int w = wh >> 3, h = wh & 7;
    const float* mw = mask + (size_t)w * 2401;
    float* out = comb + (size_t)wh * 4096;
    for (int e = threadIdx.x; e < 49 * 64; e += 256) {
        const int n = e >> 6, m = e & 63;
        out[e] = (m < 49) ? mw[n * 49 + m] + bt[rel[n * 49 + m] * 8 + h] : 0.0f;
    }
}

// ---------------------------------------------------------------- kernel 1
// Monolithic per-window kernel. 256 thr (4 waves), wave w = heads 2w, 2w+1.
// XCD-bijective remap: blk = xcd*8 + (jj&7) + (jj>>3)*64 -> each XCD sees
// wdw in {xcd*8 .. xcd*8+7} only (comb L2-resident).
// LDS (ushort units), total 25600 ush = 51,200 B:
//   xb     [0,16384)      : x bf16 [64][256], 16B-chunk j^(n&7) swizzle
//   vtw[w] 16384 + w*2304 : [32][72] v transposed (per wave, reused h0->h1)
//   P[w]   w*4608         : [64][72] FULL, wave-private. P[3] tail overlaps
//          vtw[0] only — dead (all vf loaded pre-barrier).
//   ao     [0,16896)      : [64][264] — aliases xb/P after barrier 2
// Barriers: stage-x | GEMMs done | PV done | ao stored.
__global__ __launch_bounds__(256, 2) void k_mono(
        const ushort* __restrict__ qwb, const float* __restrict__ x,
        const float* __restrict__ qb, const float* __restrict__ comb,
        const ushort* __restrict__ pwb, const float* __restrict__ pb,
        float* __restrict__ out) {
    __shared__ ushort smem[25600];   // 51,200 B
    ushort* xb = smem;

    const int t = threadIdx.x;
    const int w = t >> 6, l = t & 63;
    const int g = l >> 4, li = l & 15;
    // XCD-bijective remap (hi = jj>>3 in [0,64), mid = xcd, lo = jj&7)
    const int bid = blockIdx.x;
    const int xcd = bid & 7, jj_ = bid >> 3;
    const int blk = xcd * 8 + (jj_ & 7) + ((jj_ >> 3) << 6);
    const int wdw = blk & 63;

    ushort* vtw = smem + 16384 + w * 2304;   // [32][72]
    ushort* P   = smem + w * 4608;           // [64][72] full, wave-private
    ushort* ao  = smem;                      // [64][264]

    const floatx4 zf = {0.f, 0.f, 0.f, 0.f};
    const float scale = 0.17677669529663687f;  // 32^-0.5

    // ---- phase 0: stage x -> xb (bf16, 16B-chunk j^(n&7) swizzle) ----
#pragma unroll
    for (int rep = 0; rep < 2; ++rep) {
        const int n = (t >> 3) + rep * 32;
        const int seg = t & 7;
        if (n < 49) {
            const float* src = x + ((size_t)blk * 49 + n) * 256 + seg * 32;
#pragma unroll
            for (int c4 = 0; c4 < 4; ++c4) {
                const float4 a  = *(const float4*)(src + c4 * 8);
                const float4 b2 = *(const float4*)(src + c4 * 8 + 4);
                uint4 u;
                u.x = cvtpk(a.x, a.y);  u.y = cvtpk(a.z, a.w);
                u.z = cvtpk(b2.x, b2.y); u.w = cvtpk(b2.z, b2.w);
                const int j = seg * 4 + c4;
                *(uint4*)(xb + n * 256 + ((j ^ (n & 7)) * 8)) = u;
            }
        } else {
            const uint4 z = {0u, 0u, 0u, 0u};
#pragma unroll
            for (int c4 = 0; c4 < 4; ++c4) {
                const int j = seg * 4 + c4;
                *(uint4*)(xb + n * 256 + ((j ^ (n & 7)) * 8)) = z;
            }
        }
    }
    __syncthreads();

    // one GEMM pass: 2 c-tiles (W rows BASE, BASE+16), acc[2][4].
    // acc[ct][nt] lane map: c = BASE + ct*16 + g*4 + r, n = nt*16 + li.
    // S19: afp batch loads pinned ahead of the MFMAs by sched_barrier(0)
    // so the 16 L2 loads issue concurrently (latency paid once per pass).
    floatx4 acc[2][4];
#define GEMM_PASS(BASE)                                                       \
    {                                                                         \
        short8 afp[8][2];                                                     \
        _Pragma("unroll")                                                     \
        for (int kt = 0; kt < 8; ++kt) {                                      \
            afp[kt][0] = *(const short8*)(qwb +                               \
                (size_t)((BASE) + li) * 256 + kt * 32 + g * 8);               \
            afp[kt][1] = *(const short8*)(qwb +                               \
                (size_t)((BASE) + 16 + li) * 256 + kt * 32 + g * 8);          \
        }                                                                     \
        __builtin_amdgcn_sched_barrier(0);                                    \
        _Pragma("unroll")                                                     \
        for (int i = 0; i < 2; ++i)                                           \
            _Pragma("unroll")                                                 \
            for (int jj = 0; jj < 4; ++jj) acc[i][jj] = zf;                   \
        _Pragma("unroll")                                                     \
        for (int kt = 0; kt < 8; ++kt) {                                      \
            _Pragma("unroll")                                                 \
            for (int nt = 0; nt < 4; ++nt) {                                  \
                const short8 bx = *(const short8*)(xb +                       \
                    (nt * 16 + li) * 256 + (((kt * 4 + g) ^ (li & 7)) * 8));  \
                acc[0][nt] = __builtin_amdgcn_mfma_f32_16x16x32_bf16(         \
                    afp[kt][0], bx, acc[0][nt], 0, 0, 0);                     \
                acc[1][nt] = __builtin_amdgcn_mfma_f32_16x16x32_bf16(         \
                    afp[kt][1], bx, acc[1][nt], 0, 0, 0);                     \
            }                                                                 \
        }                                                                     \
    }

    // acc (+bias) -> B-operand frag via in-register transpose (S10/S12-proven)
#define XPOSE_QK(CBASE, OUTF)                                                 \
    {                                                                         \
        uint2 u2[2][4];                                                       \
        _Pragma("unroll")                                                     \
        for (int ct = 0; ct < 2; ++ct) {                                      \
            const float4 b4 = *(const float4*)(qb + (CBASE) + ct * 16 + g * 4);\
            _Pragma("unroll")                                                 \
            for (int nt = 0; nt < 4; ++nt) {                                  \
                u2[ct][nt].x = cvtpk(acc[ct][nt][0] + b4.x,                   \
                                     acc[ct][nt][1] + b4.y);                  \
                u2[ct][nt].y = cvtpk(acc[ct][nt][2] + b4.z,                   \
                                     acc[ct][nt][3] + b4.w);                  \
            }                                                                 \
        }                                                                     \
        const int src0 = li + (g & 1) * 32, src1 = src0 + 16;                 \
        _Pragma("unroll")                                                     \
        for (int mt = 0; mt < 4; ++mt) {                                      \
            const uint2 a0 = shfl2(u2[0][mt], src0);                          \
            const uint2 a1 = shfl2(u2[0][mt], src1);                          \
            const uint2 b0 = shfl2(u2[1][mt], src0);                          \
            const uint2 b1 = shfl2(u2[1][mt], src1);                          \
            union { short8 s; uint32_t q[4]; } cv;                            \
            cv.q[0] = (g < 2) ? a0.x : b0.x;                                  \
            cv.q[1] = (g < 2) ? a0.y : b0.y;                                  \
            cv.q[2] = (g < 2) ? a1.x : b1.x;                                  \
            cv.q[3] = (g < 2) ? a1.y : b1.y;                                  \
            OUTF[mt] = cv.s;                                                  \
        }                                                                     \
    }

    // ---- GEMM passes for both heads (xb live throughout) ----
    short8 qf[2][4], kf[2][4], vf[2][2][2];
#pragma unroll
    for (int hh = 0; hh < 2; ++hh) {
        const int hd = w * 2 + hh;
        GEMM_PASS(hd * 32)
        XPOSE_QK(hd * 32, qf[hh])
        GEMM_PASS(256 + hd * 32)
        XPOSE_QK(256 + hd * 32, kf[hh])
        GEMM_PASS(512 + hd * 32)
        // V epilogue -> vtw (transposed [dd][n]), then frags (region reused)
#pragma unroll
        for (int ct = 0; ct < 2; ++ct) {
            const int dd0 = ct * 16 + g * 4;
            const float4 b4 = *(const float4*)(qb + 512 + hd * 32 + dd0);
#pragma unroll
            for (int nt = 0; nt < 4; ++nt) {
                const int n = nt * 16 + li;
                vtw[(dd0 + 0) * 72 + n] = f2bf(acc[ct][nt][0] + b4.x);
                vtw[(dd0 + 1) * 72 + n] = f2bf(acc[ct][nt][1] + b4.y);
                vtw[(dd0 + 2) * 72 + n] = f2bf(acc[ct][nt][2] + b4.z);
                vtw[(dd0 + 3) * 72 + n] = f2bf(acc[ct][nt][3] + b4.w);
            }
        }
#pragma unroll
        for (int ks = 0; ks < 2; ++ks)
#pragma unroll
            for (int nt = 0; nt < 2; ++nt)
                vf[hh][ks][nt] = *(const short8*)(vtw + (nt * 16 + li) * 72 +
                                                  ks * 32 + g * 8);
    }
    __syncthreads();   // xb + all vtw dead: P (aliasing them) may be written

    // ---- attention per head (S12/S15 math verbatim) ----
    floatx4 oac[2][4][2];
#pragma unroll
    for (int hh = 0; hh < 2; ++hh) {
        const int hd = w * 2 + hh;
        const float* cw = comb + (size_t)(wdw * 8 + hd) * 4096;
#pragma unroll
        for (int bq = 0; bq < 4; ++bq) {
            floatx4 sac[4];
#pragma unroll
            for (int ak = 0; ak < 4; ++ak)
                sac[ak] = __builtin_amdgcn_mfma_f32_16x16x32_bf16(
                    kf[hh][ak], qf[hh][bq], zf, 0, 0, 0);

            const int n = bq * 16 + li;
            const float* cr = cw + n * 64 + g * 4;
            const float4 c0 = *(const float4*)(cr);
            const float4 c1 = *(const float4*)(cr + 16);
            const float4 c2 = *(const float4*)(cr + 32);
            const float c3x = cr[48];
            float v[12];
            v[0]  = sac[0][0] * scale + c0.x;
            v[1]  = sac[0][1] * scale + c0.y;
            v[2]  = sac[0][2] * scale + c0.z;
            v[3]  = sac[0][3] * scale + c0.w;
            v[4]  = sac[1][0] * scale + c1.x;
            v[5]  = sac[1][1] * scale + c1.y;
            v[6]  = sac[1][2] * scale + c1.z;
            v[7]  = sac[1][3] * scale + c1.w;
            v[8]  = sac[2][0] * scale + c2.x;
            v[9]  = sac[2][1] * scale + c2.y;
            v[10] = sac[2][2] * scale + c2.z;
            v[11] = sac[2][3] * scale + c2.w;
            const float v48 = (g == 0) ? sac[3][0] * scale + c3x : -3.0e38f;
            float mx = fmaxf(fmaxf(fmaxf(v[0], v[1]), fmaxf(v[2], v[3])),
                             fmaxf(fmaxf(v[4], v[5]), fmaxf(v[6], v[7])));
            mx = fmaxf(mx, fmaxf(fmaxf(v[8], v[9]), fmaxf(v[10], v[11])));
            mx = fmaxf(mx, v48);
            mx = fmaxf(mx, __shfl_xor(mx, 16, 64));
            mx = fmaxf(mx, __shfl_xor(mx, 32, 64));
            float e[12], s = 0.f;
#pragma unroll
            for (int i = 0; i < 12; ++i) { e[i] = __expf(v[i] - mx); s += e[i]; }
            const float e48 = __expf(v48 - mx);   // exactly 0 for g>0
            s += e48;
            s += __shfl_xor(s, 16, 64);
            s += __shfl_xor(s, 32, 64);
            const float inv = 1.0f / s;
            uint2 pk;
#pragma unroll
            for (int a = 0; a < 3; ++a) {
                pk.x = cvtpk(e[a * 4 + 0] * inv, e[a * 4 + 1] * inv);
                pk.y = cvtpk(e[a * 4 + 2] * inv, e[a * 4 + 3] * inv);
                *(uint2*)(P + n * 72 + a * 16 + g * 4) = pk;
            }
            pk.x = cvtpk(e48 * inv, 0.f);
            pk.y = 0u;
            *(uint2*)(P + n * 72 + 48 + g * 4) = pk;   // cols 49..63 exact 0
        }

        // O = P V (wave-private; hh=0's PV completes before hh=1 rewrites P)
#pragma unroll
        for (int mt = 0; mt < 4; ++mt)
#pragma unroll
            for (int nt = 0; nt < 2; ++nt) oac[hh][mt][nt] = zf;
#pragma unroll
        for (int ks = 0; ks < 2; ++ks)
#pragma unroll
            for (int mt = 0; mt < 4; ++mt) {
                const short8 pf = *(const short8*)(P + (mt * 16 + li) * 72 +
                                                   ks * 32 + g * 8);
                oac[hh][mt][0] = __builtin_amdgcn_mfma_f32_16x16x32_bf16(
                    pf, vf[hh][ks][0], oac[hh][mt][0], 0, 0, 0);
                oac[hh][mt][1] = __builtin_amdgcn_mfma_f32_16x16x32_bf16(
                    pf, vf[hh][ks][1], oac[hh][mt][1], 0, 0, 0);
            }
    }

    __syncthreads();   // all waves done with P: ao may overwrite

    // ---- store O into ao[n][hd*32+dd]; zero pad rows (wave: 64 cols) ----
#pragma unroll
    for (int hh = 0; hh < 2; ++hh) {
        const int hd = w * 2 + hh;
#pragma unroll
        for (int mt = 0; mt < 4; ++mt)
#pragma unroll
            for (int rr = 0; rr < 4; ++rr) {
                const int n = mt * 16 + g * 4 + rr;
                if (n < 49) {
#pragma unroll
                    for (int nt = 0; nt < 2; ++nt)
                        ao[n * 264 + hd * 32 + nt * 16 + li] =
                            f2bf(oac[hh][mt][nt][rr]);
                }
            }
    }
    for (int idx = l; idx < 480; idx += 64) {
        const int n = 49 + (idx >> 5);
        const int du = idx & 31;
        *(uint32_t*)(ao + n * 264 + w * 64 + du * 2) = 0u;
    }
    __syncthreads();

    // ---- proj: wave w covers cols w*64..w*64+63; pacc[4][4] ----
    floatx4 pacc[4][4];
#pragma unroll
    for (int mt = 0; mt < 4; ++mt)
#pragma unroll
        for (int nt = 0; nt < 4; ++nt) pacc[mt][nt] = zf;
#pragma unroll
    for (int kt = 0; kt < 8; ++kt) {
        short8 afr[4], wfr[4];
#pragma unroll
        for (int mt = 0; mt < 4; ++mt)
            afr[mt] = *(const short8*)(ao + (mt * 16 + li) * 264 + kt * 32 + g * 8);
#pragma unroll
        for (int nt = 0; nt < 4; ++nt)
            wfr[nt] = *(const short8*)(pwb +
                (size_t)(w * 64 + nt * 16 + li) * 256 + kt * 32 + g * 8);
#pragma unroll
        for (int mt = 0; mt < 4; ++mt)
#pragma unroll
            for (int nt = 0; nt < 4; ++nt)
                pacc[mt][nt] = __builtin_amdgcn_mfma_f32_16x16x32_bf16(
                    afr[mt], wfr[nt], pacc[mt][nt], 0, 0, 0);
    }

    float* og = out + (size_t)blk * 49 * 256;
#pragma unroll
    for (int nt = 0; nt < 4; ++nt) {
        const int c = w * 64 + nt * 16 + li;
        const float bias = pb[c];
#pragma unroll
        for (int mt = 0; mt < 4; ++mt)
#pragma unroll
            for (int r = 0; r < 4; ++r) {
                const int n = mt * 16 + g * 4 + r;
                if (n < 49) og[(size_t)n * 256 + c] = pacc[mt][nt][r] + bias;
            }
    }
#undef GEMM_PASS
#undef XPOSE_QK
}

// ---------------------------------------------------------------------------
extern "C" void kernel_launch(void* const* d_in, const int* in_sizes, int n_in,
                              void* d_out, int out_size, void* d_ws, size_t ws_size,
                              hipStream_t stream) {
    const float* x      = (const float*)d_in[0];
    const float* mask   = (const float*)d_in[1];
    const int*   rel    = (const int*)d_in[2];
    const float* qkv_w  = (const float*)d_in[3];
    const float* qkv_b  = (const float*)d_in[4];
    const float* proj_w = (const float*)d_in[5];
    const float* proj_b = (const float*)d_in[6];
    const float* bt     = (const float*)d_in[7];
    float* out = (float*)d_out;

    // ws layout (bytes); total = 8,912,896 (~8.5 MiB)
    char* ws = (char*)d_ws;
    ushort* qwb  = (ushort*)(ws);                  // 768*256 bf16   (393216 B)
    ushort* pwb  = (ushort*)(ws + 393216);         // 256*256 bf16   (131072 B)
    float*  comb = (float*) (ws + 524288);         // 512*64*64 f32  (8388608 B)
    (void)ws_size; (void)in_sizes; (void)n_in; (void)out_size;

    k_cvt_w<<<dim3(1024), dim3(256), 0, stream>>>(qkv_w, proj_w, qwb, pwb);
    k_comb <<<dim3(512),  dim3(256), 0, stream>>>(mask, rel, bt, comb);
    k_mono <<<dim3(4096), dim3(256), 0, stream>>>(qwb, x, qkv_b, comb, pwb,
                                                  proj_b, out);
}